// Round 2
// baseline (785.640 us; speedup 1.0000x reference)
//
#include <hip/hip_runtime.h>
#include <math.h>

typedef unsigned short u16;
typedef __attribute__((ext_vector_type(8))) short short8;
typedef __attribute__((ext_vector_type(4))) float f32x4;

#define AS1 __attribute__((address_space(1)))
#define AS3 __attribute__((address_space(3)))

__device__ __forceinline__ void gload_lds16(const u16* g, u16* l) {
  __builtin_amdgcn_global_load_lds((AS1 void*)g, (AS3 void*)l, 16, 0, 0);
}

__device__ __forceinline__ float bf2f(u16 u) {
  union { unsigned i; float f; } c; c.i = ((unsigned)u) << 16; return c.f;
}
__device__ __forceinline__ u16 f2bf(float f) {
  union { float f; unsigned i; } c; c.f = f;
  unsigned r = c.i + 0x7fffu + ((c.i >> 16) & 1u);
  return (u16)(r >> 16);
}

// ---------------------------------------------------------------------------
// f32 -> bf16 bulk convert, 8 elems/thread, grid-stride.
// ---------------------------------------------------------------------------
__global__ __launch_bounds__(256)
void cvt_f32_bf16_k(const float* __restrict__ src, u16* __restrict__ dst, int n8)
{
  int i = blockIdx.x * blockDim.x + threadIdx.x;
  const int stride = gridDim.x * blockDim.x;
  for (; i < n8; i += stride) {
    float4 a = ((const float4*)src)[2 * i];
    float4 b = ((const float4*)src)[2 * i + 1];
    short8 o;
    o[0] = (short)f2bf(a.x); o[1] = (short)f2bf(a.y);
    o[2] = (short)f2bf(a.z); o[3] = (short)f2bf(a.w);
    o[4] = (short)f2bf(b.x); o[5] = (short)f2bf(b.y);
    o[6] = (short)f2bf(b.z); o[7] = (short)f2bf(b.w);
    ((short8*)dst)[i] = o;
  }
}

// ---------------------------------------------------------------------------
// GEMM C[M][N] = A[M][K](bf16) @ W^T, W stored [N][K] row-major (bf16).
// MODE 0: fused QKV (N=6144: cols 0..4095 wq, 4096..5119 wk, 5120..6143 wv)
// MODE 1: plain (N=4096, W0 only). OutT: u16 (bf16) or float.
// m97 structure: 128x128 tile, BK=32, 4 waves, global_load_lds width 16.
// ---------------------------------------------------------------------------
template<int MODE, typename OutT>
__global__ __launch_bounds__(256, 2)
void gemm_bt(const u16* __restrict__ A, const u16* __restrict__ W0,
             const u16* __restrict__ W1, const u16* __restrict__ W2,
             OutT* __restrict__ C)
{
  constexpr int K = 4096;
  constexpr int LDC = (MODE == 0) ? 6144 : 4096;

  __shared__ __align__(16) u16 sA[128 * 32];
  __shared__ __align__(16) u16 sB[128 * 32];

  const int tid = threadIdx.x;
  const int wid = tid >> 6, lane = tid & 63;
  const int g = lane >> 4, li = lane & 15;
  const int bn = blockIdx.x, bm = blockIdx.y;
  const int wr = wid >> 1, wc = wid & 1;
  const int n0 = bn * 128;

  const u16* Wp; int nrow0;
  if (MODE == 0) {
    if (n0 < 4096)      { Wp = W0; nrow0 = n0; }
    else if (n0 < 5120) { Wp = W1; nrow0 = n0 - 4096; }
    else                { Wp = W2; nrow0 = n0 - 5120; }
  } else { Wp = W0; nrow0 = n0; }

  const u16* aptr = A  + (size_t)(bm * 128 + (tid >> 2)) * K + (tid & 3) * 8;
  const u16* bptr = Wp + (size_t)(nrow0   + (tid >> 2)) * K + (tid & 3) * 8;
  u16* sAw = sA + wid * 512;   // wave-uniform LDS base
  u16* sBw = sB + wid * 512;

  f32x4 acc[4][4] = {};

  for (int k0 = 0; k0 < K; k0 += 32) {
    gload_lds16(aptr + k0,           sAw);          // rows 0..63
    gload_lds16(aptr + k0 + 64 * K,  sAw + 2048);   // rows 64..127
    gload_lds16(bptr + k0,           sBw);
    gload_lds16(bptr + k0 + 64 * K,  sBw + 2048);
    __syncthreads();   // compiler drains vmcnt(0) before barrier

    short8 af[4], bfv[4];
#pragma unroll
    for (int m = 0; m < 4; ++m)
      af[m]  = *(const short8*)(sA + (wr * 64 + m * 16 + li) * 32 + g * 8);
#pragma unroll
    for (int n = 0; n < 4; ++n)
      bfv[n] = *(const short8*)(sB + (wc * 64 + n * 16 + li) * 32 + g * 8);
#pragma unroll
    for (int m = 0; m < 4; ++m)
#pragma unroll
      for (int n = 0; n < 4; ++n)
        acc[m][n] = __builtin_amdgcn_mfma_f32_16x16x32_bf16(af[m], bfv[n], acc[m][n], 0, 0, 0);
    __syncthreads();
  }

#pragma unroll
  for (int m = 0; m < 4; ++m)
#pragma unroll
    for (int n = 0; n < 4; ++n)
#pragma unroll
      for (int j = 0; j < 4; ++j) {
        int row = bm * 128 + wr * 64 + m * 16 + g * 4 + j;
        int col = n0 + wc * 64 + n * 16 + li;
        float v = acc[m][n][j];
        if constexpr (sizeof(OutT) == 2) C[(size_t)row * LDC + col] = (OutT)f2bf(v);
        else                             C[(size_t)row * LDC + col] = (OutT)v;
      }
}

// ---------------------------------------------------------------------------
// Per-head RMSNorm + RoPE. One wave per head-row; lane l holds d=l and d=l+64
// (the RoPE rotate_half pair). norm weights are f32 inputs.
// ---------------------------------------------------------------------------
__global__ __launch_bounds__(256)
void norm_rope(const u16* __restrict__ qkv, const float* __restrict__ qw,
               const float* __restrict__ kw, u16* __restrict__ Qo,
               u16* __restrict__ Ko)
{
  const int tid = threadIdx.x;
  const int wid = tid >> 6, l = tid & 63;
  const int idx = blockIdx.x * 4 + wid;

  const u16* src; const float* w; u16* dst; int t;
  if (idx < 131072) {                       // q rows: B*T*32
    int row = idx >> 5, h = idx & 31;
    int b = row >> 11; t = row & 2047;
    src = qkv + (size_t)row * 6144 + h * 128;
    w = qw;
    dst = Qo + (((size_t)(b * 32 + h)) * 2048 + t) * 128;
  } else {                                  // k rows: B*T*8
    int j = idx - 131072;
    int row = j >> 3, hk = j & 7;
    int b = row >> 11; t = row & 2047;
    src = qkv + (size_t)row * 6144 + 4096 + hk * 128;
    w = kw;
    dst = Ko + (((size_t)(b * 8 + hk)) * 2048 + t) * 128;
  }

  float x1 = bf2f(src[l]), x2 = bf2f(src[l + 64]);
  float ss = x1 * x1 + x2 * x2;
#pragma unroll
  for (int off = 32; off; off >>= 1) ss += __shfl_xor(ss, off);
  float rn = rsqrtf(ss * (1.0f / 128.0f) + 1e-6f);
  float y1 = x1 * rn * w[l];
  float y2 = x2 * rn * w[l + 64];

  // inv_freq = theta^(-l/64); ln(1e6)/64 = 0.21586735246819178
  float ang = (float)t * expf((float)l * -0.21586735246819178f);
  float c = cosf(ang), s = sinf(ang);
  dst[l]      = f2bf(y1 * c - y2 * s);
  dst[l + 64] = f2bf(y2 * c + y1 * s);
}

// ---------------------------------------------------------------------------
// V transpose: qkv V-cols [B*T][5120+hkv*128+d] -> Vt [B][8][128][T]
// ---------------------------------------------------------------------------
__global__ __launch_bounds__(256)
void transpose_v(const u16* __restrict__ qkv, u16* __restrict__ Vt)
{
  const int tblk = blockIdx.x, bh = blockIdx.y;
  const int b = bh >> 3, hk = bh & 7;
  const int tid = threadIdx.x;
  __shared__ __align__(16) u16 tile[64][136];   // 64 t x 128 d, padded

#pragma unroll
  for (int r = 0; r < 4; ++r) {
    int u = tid + r * 256;          // 16B unit: 16 units per t-row
    int row = u >> 4, cu = u & 15;
    short8 v = *(const short8*)(qkv + (size_t)(b * 2048 + tblk * 64 + row) * 6144
                                + 5120 + hk * 128 + cu * 8);
    *(short8*)(&tile[row][cu * 8]) = v;
  }
  __syncthreads();
#pragma unroll
  for (int it = 0; it < 4; ++it) {
    int u = tid + it * 256;         // (d, t-group of 8): 128*8 units
    int d = u & 127, tg = u >> 7;
    short8 wv8;
#pragma unroll
    for (int j = 0; j < 8; ++j) wv8[j] = (short)tile[tg * 8 + j][d];
    *(short8*)(Vt + ((size_t)(b * 8 + hk) * 128 + d) * 2048 + tblk * 64 + tg * 8) = wv8;
  }
}

// ---------------------------------------------------------------------------
// Causal flash attention. Grid (T/64, B*Hq), 256 thr = 4 waves x 16 q-rows.
// K tile [64][128] and V^T tile [128][64] staged via global_load_lds with the
// G4 XOR swizzle pre-applied to the GLOBAL source address (linear LDS dest),
// de-swizzled on the ds_read side.
// ---------------------------------------------------------------------------
__global__ __launch_bounds__(256, 2)
void attn_fwd(const u16* __restrict__ Q, const u16* __restrict__ Kc,
              const u16* __restrict__ Vt, u16* __restrict__ O)
{
  const int qt = blockIdx.x, bh = blockIdx.y;
  const int b = bh >> 5, h = bh & 31, hkv = h >> 2;
  const int tid = threadIdx.x, wid = tid >> 6, lane = tid & 63;
  const int g = lane >> 4, li = lane & 15;

  __shared__ __align__(16) u16 sK[64 * 128];
  __shared__ __align__(16) u16 sV[128 * 64];
  __shared__ __align__(16) u16 sP[4][16][72];   // per-wave P, +8 pad

  const size_t kvbase = ((size_t)(b * 8 + hkv)) * 2048 * 128;
  const size_t vtbase = ((size_t)(b * 8 + hkv)) * 128 * 2048;

  // Q fragments, hoisted (lane: row=li, d = kk*32 + g*8 .. +7)
  const u16* qrow = Q + (((size_t)(b * 32 + h)) * 2048 + qt * 64 + wid * 16 + li) * 128;
  short8 qf[4];
#pragma unroll
  for (int kk = 0; kk < 4; ++kk) qf[kk] = *(const short8*)(qrow + kk * 32 + g * 8);

  f32x4 oacc[8] = {};
  float mrun[4], lrun[4];
#pragma unroll
  for (int r = 0; r < 4; ++r) { mrun[r] = -INFINITY; lrun[r] = 0.f; }
  const float scale = 0.08838834764831845f;   // 128^-0.5

  for (int kt = 0; kt <= qt; ++kt) {
    const int kv0 = kt * 64;
    // stage K [64][128]: src address pre-swizzled so linear LDS holds swizzle
#pragma unroll
    for (int r = 0; r < 4; ++r) {
      int u = tid + r * 256;
      int row = u >> 4, c16 = u & 15;
      int sc16 = c16 ^ (row & 7);
      gload_lds16(Kc + kvbase + (size_t)(kv0 + row) * 128 + sc16 * 8,
                  sK + r * 2048 + wid * 512);
    }
    // stage V^T [128][64]
#pragma unroll
    for (int r = 0; r < 4; ++r) {
      int u = tid + r * 256;
      int row = u >> 3, c16 = u & 7;
      int sc16 = c16 ^ (row & 7);
      gload_lds16(Vt + vtbase + (size_t)row * 2048 + kv0 + sc16 * 8,
                  sV + r * 2048 + wid * 512);
    }
    __syncthreads();

    // S = Q K^T   (16 MFMA)
    f32x4 sacc[4] = {};
#pragma unroll
    for (int n = 0; n < 4; ++n) {
      int krow = n * 16 + li;
#pragma unroll
      for (int kk = 0; kk < 4; ++kk) {
        int c16 = (kk * 4 + g) ^ (krow & 7);
        short8 kf = *(const short8*)(sK + krow * 128 + c16 * 8);
        sacc[n] = __builtin_amdgcn_mfma_f32_16x16x32_bf16(qf[kk], kf, sacc[n], 0, 0, 0);
      }
    }

    // scale + causal mask (accumulator: row = g*4+r, col = n*16+li)
    const int qrow0 = qt * 64 + wid * 16 + g * 4;
    const bool diag = (kt == qt);
    float sc[4][4];
#pragma unroll
    for (int n = 0; n < 4; ++n) {
      int col = kv0 + n * 16 + li;
#pragma unroll
      for (int r = 0; r < 4; ++r) {
        float v = sacc[n][r] * scale;
        if (diag && col > qrow0 + r) v = -INFINITY;
        sc[n][r] = v;
      }
    }

    // online softmax over 16-lane groups
    float corr[4];
#pragma unroll
    for (int r = 0; r < 4; ++r) {
      float m = fmaxf(fmaxf(sc[0][r], sc[1][r]), fmaxf(sc[2][r], sc[3][r]));
#pragma unroll
      for (int off = 1; off < 16; off <<= 1) m = fmaxf(m, __shfl_xor(m, off));
      float mn = fmaxf(mrun[r], m);
      corr[r] = __expf(mrun[r] - mn);
      mrun[r] = mn;
    }
    float psum[4] = {0.f, 0.f, 0.f, 0.f};
#pragma unroll
    for (int n = 0; n < 4; ++n)
#pragma unroll
      for (int r = 0; r < 4; ++r) {
        float p = __expf(sc[n][r] - mrun[r]);
        psum[r] += p;
        sP[wid][g * 4 + r][n * 16 + li] = f2bf(p);
      }
#pragma unroll
    for (int r = 0; r < 4; ++r) {
      float s = psum[r];
#pragma unroll
      for (int off = 1; off < 16; off <<= 1) s += __shfl_xor(s, off);
      lrun[r] = lrun[r] * corr[r] + s;
#pragma unroll
      for (int dt = 0; dt < 8; ++dt) oacc[dt][r] *= corr[r];
    }

    // O += P @ V   (16 MFMA)
#pragma unroll
    for (int ks = 0; ks < 2; ++ks) {
      short8 pf = *(const short8*)(&sP[wid][li][ks * 32 + g * 8]);
#pragma unroll
      for (int dt = 0; dt < 8; ++dt) {
        int vrow = dt * 16 + li;
        int c16 = (ks * 4 + g) ^ (vrow & 7);
        short8 vf = *(const short8*)(sV + vrow * 64 + c16 * 8);
        oacc[dt] = __builtin_amdgcn_mfma_f32_16x16x32_bf16(pf, vf, oacc[dt], 0, 0, 0);
      }
    }
    __syncthreads();
  }

  float inv[4];
#pragma unroll
  for (int r = 0; r < 4; ++r) inv[r] = 1.f / lrun[r];
  const size_t orow0 = (size_t)(b * 2048 + qt * 64 + wid * 16 + g * 4);
#pragma unroll
  for (int dt = 0; dt < 8; ++dt)
#pragma unroll
    for (int r = 0; r < 4; ++r)
      O[(orow0 + r) * 4096 + h * 128 + dt * 16 + li] = f2bf(oacc[dt][r] * inv[r]);
}

// ---------------------------------------------------------------------------
extern "C" void kernel_launch(void* const* d_in, const int* in_sizes, int n_in,
                              void* d_out, int out_size, void* d_ws, size_t ws_size,
                              hipStream_t stream) {
  const float* hs  = (const float*)d_in[0];
  const float* wq  = (const float*)d_in[1];
  const float* wk  = (const float*)d_in[2];
  const float* wv  = (const float*)d_in[3];
  const float* wo  = (const float*)d_in[4];
  const float* qnw = (const float*)d_in[5];
  const float* knw = (const float*)d_in[6];
  float* out = (float*)d_out;

  char* ws = (char*)d_ws;
  u16* qkv = (u16*)(ws);                  // [4096][6144] bf16   50.33 MB
  u16* qr  = (u16*)(ws + 50331648);       // [2][32][2048][128]  33.55 MB
  u16* kr  = (u16*)(ws + 83886080);       // [2][8][2048][128]    8.39 MB
  u16* vt  = (u16*)(ws + 92274688);       // [2][8][128][2048]    8.39 MB
  u16* hsb = (u16*)(ws + 100663296);      // hs bf16             33.55 MB
  u16* wqb = (u16*)(ws + 134217728);      // wq bf16             33.55 MB
  u16* wkb = (u16*)(ws + 167772160);      // wk bf16              8.39 MB
  u16* wvb = (u16*)(ws + 176160768);      // wv bf16              8.39 MB
  u16* ao  = (u16*)(ws);                  // attn out reuses dead qkv region
  u16* wob = qr;                          // wo bf16 reuses dead qr region

  cvt_f32_bf16_k<<<dim3(2048), dim3(256), 0, stream>>>(hs, hsb, 16777216 / 8);
  cvt_f32_bf16_k<<<dim3(2048), dim3(256), 0, stream>>>(wq, wqb, 16777216 / 8);
  cvt_f32_bf16_k<<<dim3(1024), dim3(256), 0, stream>>>(wk, wkb, 4194304 / 8);
  cvt_f32_bf16_k<<<dim3(1024), dim3(256), 0, stream>>>(wv, wvb, 4194304 / 8);

  gemm_bt<0, u16><<<dim3(48, 32), dim3(256), 0, stream>>>(hsb, wqb, wkb, wvb, qkv);
  norm_rope<<<dim3(40960), dim3(256), 0, stream>>>(qkv, qnw, knw, qr, kr);
  transpose_v<<<dim3(32, 16), dim3(256), 0, stream>>>(qkv, vt);
  attn_fwd<<<dim3(32, 64), dim3(256), 0, stream>>>(qr, kr, vt, ao);

  cvt_f32_bf16_k<<<dim3(2048), dim3(256), 0, stream>>>(wo, wob, 16777216 / 8);
  gemm_bt<1, float><<<dim3(32, 32), dim3(256), 0, stream>>>(ao, wob, nullptr, nullptr, out);
}